// Round 1
// baseline (60202.997 us; speedup 1.0000x reference)
//
#include <hip/hip_runtime.h>
#include <math.h>

// Deep ESN reservoir extractor, fp32, persistent wavefront-pipelined kernel.
// layer l at tick tau computes t = tau - l  ->  1 grid barrier per tick.
// Weights LDS-resident (64KB/block, 2 blocks/CU, all 512 blocks co-resident).

#define TT    512
#define RDIM  1024
#define EDIM  256
#define NL    4
#define BB    32
#define NBLK  512          // 128 blocks per layer
#define JW    8            // output columns per block
#define HDIM  (RDIM * NL)  // 4096

#define S_ELEMS   (2 * NL * RDIM * BB)   // double-buffered states, [p][l][k][b]
#define FIN_ELEMS (BB * HDIM)

// ---------------------------------------------------------------- gather ----
// xe[t][k][b] = embed[x[b][t]][k]   (transposed so reservoir reads are coalesced)
__global__ void gather_kernel(const int* __restrict__ x,
                              const float* __restrict__ embed,
                              float* __restrict__ xe)
{
    __shared__ int   ids[BB];
    __shared__ float sh[BB * (EDIM + 1)];   // +1 pad: conflict-free transpose
    const int t = blockIdx.x, tid = threadIdx.x;
    if (tid < BB) ids[tid] = x[tid * TT + t];
    __syncthreads();
    for (int r = 0; r < BB; ++r)            // coalesced row loads
        sh[r * (EDIM + 1) + tid] = embed[ids[r] * EDIM + tid];
    __syncthreads();
    for (int kk = 0; kk < EDIM / 8; ++kk) { // coalesced over b
        int k = kk * 8 + (tid >> 5), b = tid & 31;
        xe[(t * EDIM + k) * BB + b] = sh[b * (EDIM + 1) + k];
    }
}

// ------------------------------------------------------------- reservoir ----
__global__ __launch_bounds__(256, 2) void reservoir_kernel(
    const float* __restrict__ Win0, const float* __restrict__ WinR,
    const float* __restrict__ Rst,  const float* __restrict__ xe,
    float* __restrict__ S, float* __restrict__ Fin, unsigned* __restrict__ cnt)
{
    __shared__ float Wlds[2048 * JW];       // 64 KB exactly
    const int tid   = threadIdx.x;
    const int blk   = blockIdx.x;
    const int layer = blk >> 7;
    const int j0    = (blk & 127) * JW;
    const int Kin   = (layer == 0) ? EDIM : RDIM;

    // ---- one-time weight slice load: rows [0,1024)=R_stack, [1024,..)=Win ----
    for (int idx = tid; idx < (RDIM + Kin) * JW; idx += 256) {
        int k = idx >> 3, j = idx & 7;
        float wv;
        if (k < RDIM) wv = Rst[(layer * RDIM + k) * RDIM + j0 + j];
        else {
            int k2 = k - RDIM;
            wv = (layer == 0) ? Win0[k2 * RDIM + j0 + j]
                              : WinR[((layer - 1) * RDIM + k2) * RDIM + j0 + j];
        }
        Wlds[idx] = wv;
    }
    __syncthreads();

    // lane roles: wave w owns batch rows [8w,8w+8); within wave:
    // rep = lam&7 (8-way k-split, fine interleave), u = lam>>3 selects cell group
    const int w   = tid >> 6;
    const int lam = tid & 63;
    const int rep = lam & 7;
    const int u   = lam >> 3;
    const int jp  = u & 3;                  // j pair -> j = 2jp, 2jp+1
    const int bh  = u >> 2;                 // b half -> b0..b0+3
    const int b0  = w * 8 + bh * 4;
    const float2* W2 = (const float2*)Wlds;

    for (int tick = 0; tick < TT + NL - 1; ++tick) {
        const int t = tick - layer;
        if (t >= 0 && t < TT) {
            const int cur = tick & 1, prv = cur ^ 1;
            const float4* ownp = (const float4*)(S + (prv * NL + layer) * RDIM * BB);
            const float4* inpp = (layer == 0)
                ? (const float4*)(xe + t * (EDIM * BB))
                : (const float4*)(S + (prv * NL + (layer - 1)) * RDIM * BB);

            float acc[8] = {0.f,0.f,0.f,0.f,0.f,0.f,0.f,0.f};

            #pragma unroll 8
            for (int kk = 0; kk < RDIM / 8; ++kk) {       // own state x R_stack
                int k = kk * 8 + rep;
                float4 v = ownp[k * 8 + w * 2 + bh];
                float2 wv = W2[k * 4 + jp];
                acc[0] += v.x * wv.x; acc[1] += v.x * wv.y;
                acc[2] += v.y * wv.x; acc[3] += v.y * wv.y;
                acc[4] += v.z * wv.x; acc[5] += v.z * wv.y;
                acc[6] += v.w * wv.x; acc[7] += v.w * wv.y;
            }
            #pragma unroll 8
            for (int kk = 0; kk < Kin / 8; ++kk) {        // layer input x Win
                int k = kk * 8 + rep;
                float4 v = inpp[k * 8 + w * 2 + bh];
                float2 wv = W2[(RDIM + k) * 4 + jp];
                acc[0] += v.x * wv.x; acc[1] += v.x * wv.y;
                acc[2] += v.y * wv.x; acc[3] += v.y * wv.y;
                acc[4] += v.z * wv.x; acc[5] += v.z * wv.y;
                acc[6] += v.w * wv.x; acc[7] += v.w * wv.y;
            }
            // allreduce across rep (lane bits 0..2)
            #pragma unroll
            for (int m = 1; m <= 4; m <<= 1)
                #pragma unroll
                for (int r = 0; r < 8; ++r) acc[r] += __shfl_xor(acc[r], m, 64);

            if (rep == 0) {
                float4 o0, o1;
                o0.x = tanhf(acc[0]); o1.x = tanhf(acc[1]);
                o0.y = tanhf(acc[2]); o1.y = tanhf(acc[3]);
                o0.z = tanhf(acc[4]); o1.z = tanhf(acc[5]);
                o0.w = tanhf(acc[6]); o1.w = tanhf(acc[7]);
                float* dst = S + ((cur * NL + layer) * RDIM + (j0 + 2 * jp)) * BB + b0;
                *(float4*)(dst)      = o0;
                *(float4*)(dst + BB) = o1;
                if (t == TT - 1) {                         // final states for LN
                    int jj = layer * RDIM + j0 + 2 * jp;
                    Fin[(b0 + 0) * HDIM + jj] = o0.x; Fin[(b0 + 0) * HDIM + jj + 1] = o1.x;
                    Fin[(b0 + 1) * HDIM + jj] = o0.y; Fin[(b0 + 1) * HDIM + jj + 1] = o1.y;
                    Fin[(b0 + 2) * HDIM + jj] = o0.z; Fin[(b0 + 2) * HDIM + jj + 1] = o1.z;
                    Fin[(b0 + 3) * HDIM + jj] = o0.w; Fin[(b0 + 3) * HDIM + jj + 1] = o1.w;
                }
            }
        }
        // ---- grid barrier (monotone counter, device scope, bounded spin) ----
        __syncthreads();
        if (tid == 0) {
            __threadfence();                 // release: drain stores, wb L2
            atomicAdd(cnt, 1u);
            unsigned want = (unsigned)(tick + 1) * (unsigned)NBLK;
            int guard = 0;
            while (__hip_atomic_load(cnt, __ATOMIC_ACQUIRE,
                                     __HIP_MEMORY_SCOPE_AGENT) < want) {
                __builtin_amdgcn_s_sleep(2);
                if (++guard > (1 << 18)) break;   // safety valve: no GPU hang
            }
            __threadfence();
        }
        __syncthreads();
    }
}

// ------------------------------------------------------------- layernorm ----
__global__ void ln_kernel(const float* __restrict__ Fin,
                          const float* __restrict__ gamma,
                          const float* __restrict__ beta,
                          float* __restrict__ out)
{
    const int r = blockIdx.x, tid = threadIdx.x;
    const float* row = Fin + r * HDIM;
    float s = 0.f, s2 = 0.f;
    for (int i = tid; i < HDIM; i += 256) { float v = row[i]; s += v; s2 += v * v; }
    for (int off = 32; off; off >>= 1) {
        s  += __shfl_down(s,  off, 64);
        s2 += __shfl_down(s2, off, 64);
    }
    __shared__ float rs[4], rs2[4];
    __shared__ float mu_s, rstd_s;
    if ((tid & 63) == 0) { rs[tid >> 6] = s; rs2[tid >> 6] = s2; }
    __syncthreads();
    if (tid == 0) {
        float S1 = rs[0] + rs[1] + rs[2] + rs[3];
        float S2 = rs2[0] + rs2[1] + rs2[2] + rs2[3];
        float mu = S1 / (float)HDIM;
        float var = S2 / (float)HDIM - mu * mu;
        mu_s = mu; rstd_s = rsqrtf(var + 1e-5f);
    }
    __syncthreads();
    float mu = mu_s, rstd = rstd_s;
    for (int i = tid; i < HDIM; i += 256)
        out[r * HDIM + i] = (row[i] - mu) * rstd * gamma[i] + beta[i];
}

// ----------------------------------------------------------------- launch ---
extern "C" void kernel_launch(void* const* d_in, const int* in_sizes, int n_in,
                              void* d_out, int out_size, void* d_ws, size_t ws_size,
                              hipStream_t stream)
{
    const int*   x     = (const int*)d_in[0];
    const float* embed = (const float*)d_in[1];
    const float* Win0  = (const float*)d_in[2];
    const float* WinR  = (const float*)d_in[3];
    const float* Rst   = (const float*)d_in[4];
    const float* gamma = (const float*)d_in[5];
    const float* beta  = (const float*)d_in[6];
    float* out = (float*)d_out;

    char* ws = (char*)d_ws;
    unsigned* cnt = (unsigned*)ws;                               // barrier counter
    float* S   = (float*)(ws + 256);                             // states, 1 MB
    float* Fin = (float*)(ws + 256 + (size_t)S_ELEMS * 4);       // 0.5 MB
    float* xe  = (float*)(ws + 256 + (size_t)(S_ELEMS + FIN_ELEMS) * 4); // 16.8 MB

    hipMemsetAsync(ws, 0, 256 + (size_t)S_ELEMS * 4, stream);    // zero cnt + states
    gather_kernel   <<<TT,   256, 0, stream>>>(x, embed, xe);
    reservoir_kernel<<<NBLK, 256, 0, stream>>>(Win0, WinR, Rst, xe, S, Fin, cnt);
    ln_kernel       <<<BB,   256, 0, stream>>>(Fin, gamma, beta, out);
}

// Round 2
// 8761.215 us; speedup vs baseline: 6.8715x; 6.8715x over previous
//
#include <hip/hip_runtime.h>
#include <math.h>

// Deep ESN, fp32, persistent wavefront-pipelined kernel, round 2.
// Changes vs R1: (a) fence-free cross-XCD sync: all state traffic via
// relaxed AGENT-scope atomics (write-through to coherence point; no
// threadfence/wbl2, no acquire-invalidate polling); (b) panel state layout
// S[p][l][panel][k][8b] -> every state load is 1KB contiguous per wave.

#define TT    512
#define RDIM  1024
#define EDIM  256
#define NL    4
#define BB    32
#define NBLK  512          // 128 blocks per layer
#define JW    8            // output columns per block
#define HDIM  (RDIM * NL)  // 4096
#define NPAN  4            // 4 panels of 8 batch rows
#define CSTRIDE 32         // dwords between barrier counters (128B lines)

#define S_ELEMS   (2 * NL * NPAN * RDIM * 8)   // 262144 floats, 1MB
#define FIN_ELEMS (BB * HDIM)

typedef unsigned long long ull;

__device__ __forceinline__ ull pack2(float a, float b) {
    union { float f[2]; ull u; } c; c.f[0] = a; c.f[1] = b; return c.u;
}
__device__ __forceinline__ float2 unpack2(ull u) {
    union { ull u; float2 f; } c; c.u = u; return c.f;
}

// ---------------------------------------------------------------- gather ----
// xe[t][panel][k][8b] : panel layout matching reservoir reads
__global__ void gather_kernel(const int* __restrict__ x,
                              const float* __restrict__ embed,
                              float* __restrict__ xe)
{
    __shared__ int   ids[BB];
    __shared__ float sh[BB * (EDIM + 1)];
    const int t = blockIdx.x, tid = threadIdx.x;
    if (tid < BB) ids[tid] = x[tid * TT + t];
    __syncthreads();
    for (int r = 0; r < BB; ++r)
        sh[r * (EDIM + 1) + tid] = embed[ids[r] * EDIM + tid];
    __syncthreads();
    for (int i = tid; i < NPAN * EDIM * 8; i += 256) {   // coalesced writes
        int p = i >> 11, k = (i >> 3) & (EDIM - 1), bo = i & 7;
        xe[(size_t)t * (NPAN * EDIM * 8) + i] = sh[(p * 8 + bo) * (EDIM + 1) + k];
    }
}

// ------------------------------------------------------------- reservoir ----
__global__ __launch_bounds__(256, 2) void reservoir_kernel(
    const float* __restrict__ Win0, const float* __restrict__ WinR,
    const float* __restrict__ Rst,  const float* __restrict__ xe,
    float* __restrict__ S, float* __restrict__ Fin, unsigned* __restrict__ cnt)
{
    __shared__ float Wlds[2048 * JW];       // 64 KB, row k = 8 floats (j0..j0+7)
    const int tid   = threadIdx.x;
    const int blk   = blockIdx.x;
    const int layer = blk >> 7;
    const int j0    = (blk & 127) * JW;
    const int Kin   = (layer == 0) ? EDIM : RDIM;

    // rows [0,1024) = R_stack col-slice, rows [1024,1024+Kin) = Win col-slice
    for (int idx = tid; idx < (RDIM + Kin) * JW; idx += 256) {
        int k = idx >> 3, j = idx & 7;
        float wv;
        if (k < RDIM) wv = Rst[((size_t)layer * RDIM + k) * RDIM + j0 + j];
        else {
            int k2 = k - RDIM;
            wv = (layer == 0) ? Win0[(size_t)k2 * RDIM + j0 + j]
                              : WinR[((size_t)(layer - 1) * RDIM + k2) * RDIM + j0 + j];
        }
        Wlds[idx] = wv;
    }
    __syncthreads();

    const int w   = tid >> 6;   // wave -> panel (8 batch rows)
    const int lam = tid & 63;
    const int kq  = lam >> 1;   // 32-way k split within wave
    const int bh  = lam & 1;    // which float4 of the 8-wide row

    for (int tick = 0; tick < TT + NL - 1; ++tick) {
        const int t = tick - layer;
        if (t >= 0 && t < TT) {
            const int cur = tick & 1, prv = cur ^ 1;
            const ull* ownp = (const ull*)(S + (((size_t)(prv * NL + layer) * NPAN + w) * RDIM) * 8);

            float acc[4][8];
            #pragma unroll
            for (int i = 0; i < 4; ++i)
                #pragma unroll
                for (int j = 0; j < 8; ++j) acc[i][j] = 0.f;

            // ---- own state @ R_stack rows ----
            #pragma unroll 4
            for (int kk = 0; kk < RDIM / 32; ++kk) {
                const ull* p = ownp + (size_t)kk * 128 + lam * 2;  // 1KB/wave contiguous
                ull u0 = __hip_atomic_load(p,     __ATOMIC_RELAXED, __HIP_MEMORY_SCOPE_AGENT);
                ull u1 = __hip_atomic_load(p + 1, __ATOMIC_RELAXED, __HIP_MEMORY_SCOPE_AGENT);
                float2 v0 = unpack2(u0), v1 = unpack2(u1);
                int k = kk * 32 + kq;
                float4 w0 = *(const float4*)&Wlds[k * 8];
                float4 w1 = *(const float4*)&Wlds[k * 8 + 4];
                const float vv[4] = {v0.x, v0.y, v1.x, v1.y};
                const float wr[8] = {w0.x, w0.y, w0.z, w0.w, w1.x, w1.y, w1.z, w1.w};
                #pragma unroll
                for (int i = 0; i < 4; ++i)
                    #pragma unroll
                    for (int j = 0; j < 8; ++j) acc[i][j] += vv[i] * wr[j];
            }
            // ---- layer input @ Win rows ----
            if (layer == 0) {
                const float4* inp = (const float4*)(xe + ((size_t)t * NPAN + w) * (EDIM * 8));
                #pragma unroll 4
                for (int kk = 0; kk < EDIM / 32; ++kk) {
                    float4 v = inp[kk * 64 + lam];                 // cached read, 1KB/wave
                    int k = kk * 32 + kq;
                    float4 w0 = *(const float4*)&Wlds[(RDIM + k) * 8];
                    float4 w1 = *(const float4*)&Wlds[(RDIM + k) * 8 + 4];
                    const float vv[4] = {v.x, v.y, v.z, v.w};
                    const float wr[8] = {w0.x, w0.y, w0.z, w0.w, w1.x, w1.y, w1.z, w1.w};
                    #pragma unroll
                    for (int i = 0; i < 4; ++i)
                        #pragma unroll
                        for (int j = 0; j < 8; ++j) acc[i][j] += vv[i] * wr[j];
                }
            } else {
                const ull* inp = (const ull*)(S + (((size_t)(prv * NL + layer - 1) * NPAN + w) * RDIM) * 8);
                #pragma unroll 4
                for (int kk = 0; kk < RDIM / 32; ++kk) {
                    const ull* p = inp + (size_t)kk * 128 + lam * 2;
                    ull u0 = __hip_atomic_load(p,     __ATOMIC_RELAXED, __HIP_MEMORY_SCOPE_AGENT);
                    ull u1 = __hip_atomic_load(p + 1, __ATOMIC_RELAXED, __HIP_MEMORY_SCOPE_AGENT);
                    float2 v0 = unpack2(u0), v1 = unpack2(u1);
                    int k = kk * 32 + kq;
                    float4 w0 = *(const float4*)&Wlds[(RDIM + k) * 8];
                    float4 w1 = *(const float4*)&Wlds[(RDIM + k) * 8 + 4];
                    const float vv[4] = {v0.x, v0.y, v1.x, v1.y};
                    const float wr[8] = {w0.x, w0.y, w0.z, w0.w, w1.x, w1.y, w1.z, w1.w};
                    #pragma unroll
                    for (int i = 0; i < 4; ++i)
                        #pragma unroll
                        for (int j = 0; j < 8; ++j) acc[i][j] += vv[i] * wr[j];
                }
            }
            // ---- reduce over kq (lane bits 1..5) ----
            #pragma unroll
            for (int m = 2; m <= 32; m <<= 1)
                #pragma unroll
                for (int i = 0; i < 4; ++i)
                    #pragma unroll
                    for (int j = 0; j < 8; ++j)
                        acc[i][j] += __shfl_xor(acc[i][j], m, 64);

            if (kq < 8) {                       // lane kq -> output column j0+kq
                const int j = kq;
                float o0 = tanhf(acc[0][j]), o1 = tanhf(acc[1][j]);
                float o2 = tanhf(acc[2][j]), o3 = tanhf(acc[3][j]);
                ull* dst = (ull*)(S + ((((size_t)(cur * NL + layer) * NPAN + w) * RDIM + (j0 + j)) * 8 + bh * 4));
                __hip_atomic_store(dst,     pack2(o0, o1), __ATOMIC_RELAXED, __HIP_MEMORY_SCOPE_AGENT);
                __hip_atomic_store(dst + 1, pack2(o2, o3), __ATOMIC_RELAXED, __HIP_MEMORY_SCOPE_AGENT);
                if (t == TT - 1) {
                    int jj = layer * RDIM + j0 + j;
                    int b0 = w * 8 + bh * 4;
                    Fin[(size_t)(b0 + 0) * HDIM + jj] = o0;
                    Fin[(size_t)(b0 + 1) * HDIM + jj] = o1;
                    Fin[(size_t)(b0 + 2) * HDIM + jj] = o2;
                    Fin[(size_t)(b0 + 3) * HDIM + jj] = o3;
                }
            }
        }
        // ---- fence-free grid barrier: relaxed agent atomics only ----
        __syncthreads();                          // drains every wave's vmcnt
        if (tid == 0)
            __hip_atomic_fetch_add(&cnt[(blk & 15) * CSTRIDE], 1u,
                                   __ATOMIC_RELAXED, __HIP_MEMORY_SCOPE_AGENT);
        if (tid < 64) {                           // wave 0 polls 16 counters
            const unsigned want = (unsigned)(tick + 1) * (unsigned)NBLK;
            int guard = 0;
            for (;;) {
                unsigned v = __hip_atomic_load(&cnt[(lam & 15) * CSTRIDE],
                                               __ATOMIC_RELAXED, __HIP_MEMORY_SCOPE_AGENT);
                #pragma unroll
                for (int m = 1; m <= 8; m <<= 1) v += __shfl_xor(v, m, 64);
                if (v >= want) break;
                __builtin_amdgcn_s_sleep(1);
                if (++guard > (1 << 14)) break;   // safety valve: no GPU hang
            }
        }
        __syncthreads();
    }
}

// ------------------------------------------------------------- layernorm ----
__global__ void ln_kernel(const float* __restrict__ Fin,
                          const float* __restrict__ gamma,
                          const float* __restrict__ beta,
                          float* __restrict__ out)
{
    const int r = blockIdx.x, tid = threadIdx.x;
    const float* row = Fin + (size_t)r * HDIM;
    float s = 0.f, s2 = 0.f;
    for (int i = tid; i < HDIM; i += 256) { float v = row[i]; s += v; s2 += v * v; }
    for (int off = 32; off; off >>= 1) {
        s  += __shfl_down(s,  off, 64);
        s2 += __shfl_down(s2, off, 64);
    }
    __shared__ float rs[4], rs2[4];
    __shared__ float mu_s, rstd_s;
    if ((tid & 63) == 0) { rs[tid >> 6] = s; rs2[tid >> 6] = s2; }
    __syncthreads();
    if (tid == 0) {
        float S1 = rs[0] + rs[1] + rs[2] + rs[3];
        float S2 = rs2[0] + rs2[1] + rs2[2] + rs2[3];
        float mu = S1 / (float)HDIM;
        float var = S2 / (float)HDIM - mu * mu;
        mu_s = mu; rstd_s = rsqrtf(var + 1e-5f);
    }
    __syncthreads();
    float mu = mu_s, rstd = rstd_s;
    for (int i = tid; i < HDIM; i += 256)
        out[(size_t)r * HDIM + i] = (row[i] - mu) * rstd * gamma[i] + beta[i];
}

// ----------------------------------------------------------------- launch ---
extern "C" void kernel_launch(void* const* d_in, const int* in_sizes, int n_in,
                              void* d_out, int out_size, void* d_ws, size_t ws_size,
                              hipStream_t stream)
{
    const int*   x     = (const int*)d_in[0];
    const float* embed = (const float*)d_in[1];
    const float* Win0  = (const float*)d_in[2];
    const float* WinR  = (const float*)d_in[3];
    const float* Rst   = (const float*)d_in[4];
    const float* gamma = (const float*)d_in[5];
    const float* beta  = (const float*)d_in[6];
    float* out = (float*)d_out;

    char* ws = (char*)d_ws;
    unsigned* cnt = (unsigned*)ws;                                   // 2KB + pad
    float* S   = (float*)(ws + 8192);                                // 1MB
    float* Fin = (float*)(ws + 8192 + (size_t)S_ELEMS * 4);          // 0.5MB
    float* xe  = (float*)(ws + 8192 + (size_t)(S_ELEMS + FIN_ELEMS) * 4); // 16.8MB

    hipMemsetAsync(ws, 0, 8192 + (size_t)S_ELEMS * 4, stream);       // cnt + states
    gather_kernel   <<<TT,   256, 0, stream>>>(x, embed, xe);
    reservoir_kernel<<<NBLK, 256, 0, stream>>>(Win0, WinR, Rst, xe, S, Fin, cnt);
    ln_kernel       <<<BB,   256, 0, stream>>>(Fin, gamma, beta, out);
}